// Round 6
// baseline (748.286 us; speedup 1.0000x reference)
//
#include <hip/hip_runtime.h>
#include <math.h>

#define M_ANCH   589824
#define NCLS     80
#define TOPK_N   1000
#define CAND_CAP 4096
#define NREP     16
#define NBIN     8192          /* 13-bit bins */
#define KSHIFT   19
#define G2       144           /* mega-kernel grid */
#define BT       1024          /* mega-kernel block */

#define SCALE_CLAMP_F 4.135166556742356f   /* log(1000/16) as f32 */
#define INV_IMG       (1.0f/2048.0f)

// ---------------- ws layout (bytes) ----------------
// [0,      524288)   hist replicas (16 x 8192 u32)  -- memset 0
// [524288, 524292)   cand count (u32)               -- memset 0
// [524292, 524296)   done counter (u32)             -- memset 0
// [524544, 557312)   cand keys (4096 u64)
// [557312, 685312)   sup matrix (1000*16 u64)
// [685568, 3044864)  mkeys (589824 u32, 16B-aligned)
#define WS_H1R     0
#define WS_CNT     524288
#define WS_DONE    524292
#define WS_MEMSET  524296
#define WS_CAND    524544
#define WS_SUP     557312
#define WS_MKEYS   685568

// monotone float->uint map (positive floats get top bit set)
__device__ __forceinline__ unsigned fmap(unsigned b) {
    return (b & 0x80000000u) ? ~b : (b | 0x80000000u);
}
__device__ __forceinline__ unsigned funmap(unsigned k) {
    return (k & 0x80000000u) ? (k ^ 0x80000000u) : ~k;
}

// K1: per-anchor max logit via fully-coalesced LDS staging; 13-bit LDS
// histogram flushed to 16 replicated global histograms. 256 rows/block.
__global__ __launch_bounds__(256) void k_rowmax(const float4* __restrict__ cls4,
                                                unsigned* __restrict__ mkeys,
                                                unsigned* __restrict__ h1r) {
    __shared__ unsigned lh[NBIN];      // 32 KiB
    __shared__ float stage[1280];      // 5 KiB: 64 rows x 20 f4-maxes
    int t = threadIdx.x;
    for (int b = t; b < NBIN; b += 256) lh[b] = 0;
    __syncthreads();
    int r = t >> 2, q = t & 3;
    for (int ch = 0; ch < 4; ++ch) {   // 4 chunks of 64 rows
        size_t base = (size_t)blockIdx.x * 5120 + (size_t)ch * 1280;
#pragma unroll
        for (int i = 0; i < 5; ++i) {  // 5 contiguous 4KB block-wide loads
            float4 v = cls4[base + i * 256 + t];
            stage[i * 256 + t] = fmaxf(fmaxf(v.x, v.y), fmaxf(v.z, v.w));
        }
        __syncthreads();
        float m = -INFINITY;
#pragma unroll
        for (int j = 0; j < 5; ++j) m = fmaxf(m, stage[r * 20 + q * 5 + j]);
        m = fmaxf(m, __shfl_xor(m, 1));
        m = fmaxf(m, __shfl_xor(m, 2));
        if (q == 0) {
            unsigned key = fmap(__float_as_uint(m));
            mkeys[blockIdx.x * 256 + ch * 64 + r] = key;
            atomicAdd(&lh[key >> KSHIFT], 1u);
        }
        __syncthreads();
    }
    unsigned rep = (blockIdx.x & (NREP - 1)) * NBIN;
    for (int b = t; b < NBIN; b += 256) {
        unsigned c = lh[b];
        if (c) atomicAdd(&h1r[rep + b], c);
    }
}

// K2 "mega": per-block redundant threshold-find + gather; last-finishing
// block runs rank+decode+sup+NMS. No grid sync needed (threadfence+done).
#define SM_BYTES 52768
__global__ __launch_bounds__(1024) void k_mega(const uint4* __restrict__ mk4,
                                               const float* __restrict__ cls,
                                               const float4* __restrict__ reg4,
                                               const float4* __restrict__ anch4,
                                               const unsigned* __restrict__ h1r,
                                               unsigned* __restrict__ cnt,
                                               unsigned* __restrict__ done,
                                               unsigned long long* __restrict__ cand_g,
                                               unsigned long long* __restrict__ sup,
                                               float* __restrict__ out) {
    __shared__ __align__(16) char smraw[SM_BYTES];
    __shared__ unsigned s_gbin, s_base, s_old;
    __shared__ unsigned s_wsum[16];
    int t = threadIdx.x;
    int lane = t & 63, wid = t >> 6;

    // ---- Phase A: redundant find (identical result in every block) ----
    unsigned* hist = (unsigned*)smraw;            // 8192 u32
    unsigned* csum = (unsigned*)(smraw + 32768);  // 256 u32
    for (int b = t; b < NBIN; b += BT) {
        unsigned s = 0;
#pragma unroll
        for (int r = 0; r < NREP; ++r) s += h1r[r * NBIN + b];
        hist[b] = s;
    }
    __syncthreads();
    if (t < 256) {
        unsigned cs = 0;
        for (int k = 0; k < 32; ++k) cs += hist[t * 32 + k];
        csum[t] = cs;
    }
    __syncthreads();
    if (t == 0) {
        unsigned cum = 0, above = 0;
        int C = 0;
        for (int c = 255; c >= 0; --c) {
            if (cum + csum[c] >= TOPK_N || c == 0) { C = c; above = cum; break; }
            cum += csum[c];
        }
        int B = C * 32;
        unsigned cum2 = above;
        for (int b = C * 32 + 31; b >= C * 32; --b) {
            cum2 += hist[b];
            if (cum2 >= TOPK_N) { B = b; break; }
            if (b == C * 32) B = b;
        }
        s_gbin = (B >= 1) ? (unsigned)(B - 1) : 0u;
    }
    __syncthreads();
    unsigned gb = s_gbin;

    // ---- Phase B: gather slice (1 uint4 = 4 keys per thread) ----
    uint4 kv = mk4[blockIdx.x * BT + t];
    unsigned keys[4] = {kv.x, kv.y, kv.z, kv.w};
    unsigned lc = 0, selq[4];
#pragma unroll
    for (unsigned q = 0; q < 4; ++q)
        if ((keys[q] >> KSHIFT) >= gb) selq[lc++] = q;
    unsigned pre = lc;
#pragma unroll
    for (int d = 1; d < 64; d <<= 1) {
        unsigned v = __shfl_up(pre, d);
        if (lane >= d) pre += v;
    }
    if (lane == 63) s_wsum[wid] = pre;   // wave total
    unsigned mypre = pre - lc;
    __syncthreads();
    if (t == 0) {
        unsigned s = 0;
        for (int w = 0; w < 16; ++w) { unsigned v = s_wsum[w]; s_wsum[w] = s; s += v; }
        s_base = s ? atomicAdd(cnt, s) : 0u;
    }
    __syncthreads();
    unsigned base = s_base + s_wsum[wid] + mypre;
    for (unsigned j = 0; j < lc; ++j) {
        unsigned pos = base + j;
        if (pos < CAND_CAP) {
            unsigned q = selq[j];
            unsigned i = ((unsigned)blockIdx.x * BT + (unsigned)t) * 4u + q;
            float m = __uint_as_float(funmap(keys[q]));
            // emulate np float32 sigmoid pipeline (correctly-rounded exp):
            float e = (float)exp(-(double)m);
            float sc = 1.0f / (1.0f + e);
            cand_g[pos] = ((unsigned long long)__float_as_uint(sc) << 32)
                          | (unsigned)(~i);
        }
    }

    // ---- last-block handshake ----
    __threadfence();
    __syncthreads();
    if (t == 0) s_old = atomicAdd(done, 1u);
    __syncthreads();
    if (s_old != G2 - 1) return;
    __threadfence();

    // ================= TAIL (one block, 1024 threads) =================
    unsigned long long* sh_cand = (unsigned long long*)smraw;      // 32 KiB
    float4* sh_box = (float4*)(smraw + 32768);                     // 16 KiB
    int*    sh_lab = (int*)(smraw + 48768);                        //  4 KiB
    unsigned n = atomicAdd(cnt, 0u);
    if (n > CAND_CAP) n = CAND_CAP;
    __syncthreads();   // all lanes done with phase-A/B smraw views
    for (int k = t; k < (int)n; k += BT) sh_cand[k] = cand_g[k];
    __syncthreads();

    // rank-by-count (keys unique) + decode into output slot
    for (int k = t; k < (int)n; k += BT) {
        unsigned long long key = sh_cand[k];
        int rank = 0;
        for (int j = 0; j < (int)n; ++j) rank += (sh_cand[j] > key) ? 1 : 0;
        if (rank >= TOPK_N) continue;
        int r = rank;
        unsigned idx = ~(unsigned)(key & 0xFFFFFFFFull);
        float sc = __uint_as_float((unsigned)(key >> 32));
        const float* row = cls + (size_t)idx * NCLS;
        float best = -INFINITY;
        int lbl = 0;
        for (int c = 0; c < NCLS; ++c) {
            float v = row[c];
            if (v > best) { best = v; lbl = c; }
        }
        float4 rg = reg4[idx];
        float4 an = anch4[idx];
        float ox = fminf(fmaxf(rg.x * an.z, -32.0f), 32.0f);
        float oy = fminf(fmaxf(rg.y * an.w, -32.0f), 32.0f);
        float cx = an.x + ox, cy = an.y + oy;
        float w = an.z * expf(fminf(rg.z, SCALE_CLAMP_F));
        float h = an.w * expf(fminf(rg.w, SCALE_CLAMP_F));
        float x1 = fminf(fmaxf((cx - 0.5f * w) * INV_IMG, 0.0f), 1.0f);
        float y1 = fminf(fmaxf((cy - 0.5f * h) * INV_IMG, 0.0f), 1.0f);
        float x2 = fminf(fmaxf((cx + 0.5f * w) * INV_IMG, 0.0f), 1.0f);
        float y2 = fminf(fmaxf((cy + 0.5f * h) * INV_IMG, 0.0f), 1.0f);
        out[r * 4 + 0] = x1;
        out[r * 4 + 1] = y1;
        out[r * 4 + 2] = x2;
        out[r * 4 + 3] = y2;
        out[4 * TOPK_N + r] = sc;
        out[5 * TOPK_N + r] = (float)lbl;
        sh_box[r] = make_float4(x1, y1, x2, y2);
        sh_lab[r] = lbl | ((sc >= 0.05f) ? 256 : 0);
    }
    __syncthreads();

    // suppression matrix, lower-triangle words only (word c <= i>>6)
    for (int task = t; task < TOPK_N * 16; task += BT) {
        int i = task >> 4, c = task & 15;
        if (c > (i >> 6)) continue;
        float4 bi = sh_box[i];
        float ai = (bi.z - bi.x) * (bi.w - bi.y);
        int li = sh_lab[i] & 0xFF;
        unsigned long long word = 0ull;
        int jmax = c * 64 + 64; if (jmax > TOPK_N) jmax = TOPK_N;
        for (int j = c * 64; j < jmax; ++j) {
            float4 bj = sh_box[j];
            float aj = (bj.z - bj.x) * (bj.w - bj.y);
            float xx1 = fmaxf(bi.x, bj.x), yy1 = fmaxf(bi.y, bj.y);
            float xx2 = fminf(bi.z, bj.z), yy2 = fminf(bi.w, bj.w);
            float w = fmaxf(1e-10f, xx2 - xx1);
            float h = fmaxf(1e-10f, yy2 - yy1);
            float inter = w * h;
            float iou = inter / (ai + aj - inter + 1e-10f);
            if ((iou > 0.6f) && ((sh_lab[j] & 0xFF) == li))
                word |= (1ull << (j & 63));
        }
        sup[(size_t)i * 16 + c] = word;
    }
    __syncthreads();

    // greedy NMS on wave 0 (fast path when no intra-chunk edges)
    if (t < 64) {
        unsigned long long kw[16];
#pragma unroll
        for (int c = 0; c < 16; ++c) kw[c] = 0ull;
        unsigned long long lowmask = (lane == 0) ? 0ull : (~0ull >> (64 - lane));
        for (int c = 0; c < 16; ++c) {
            int b = c * 64 + lane;
            bool v = false;
            bool ext = false;
            unsigned long long m = 0ull;
            if (b < TOPK_N) {
                v = ((sh_lab[b] >> 8) & 1) != 0;
                const unsigned long long* rowp = sup + (size_t)b * 16;
                for (int w = 0; w < c; ++w) ext = ext || ((rowp[w] & kw[w]) != 0ull);
                m = rowp[c];
            }
            unsigned long long inchunk = m & lowmask;
            bool mykeep;
            if (__ballot(inchunk != 0ull) == 0ull) {
                mykeep = v && !ext;
            } else {
                mykeep = false;
                for (int i = 0; i < 64; ++i) {
                    unsigned long long ball = __ballot(mykeep);
                    if (lane == i) mykeep = v && !ext && ((ball & inchunk) == 0ull);
                }
            }
            unsigned long long ball2 = __ballot(mykeep);
            kw[c] = ball2;
            if (b < TOPK_N)
                out[6 * TOPK_N + b] = ((ball2 >> lane) & 1ull) ? 1.0f : 0.0f;
        }
    }
}

extern "C" void kernel_launch(void* const* d_in, const int* in_sizes, int n_in,
                              void* d_out, int out_size, void* d_ws, size_t ws_size,
                              hipStream_t stream) {
    const float* cls  = (const float*)d_in[0];
    const float* reg  = (const float*)d_in[1];
    const float* anch = (const float*)d_in[2];
    float* out = (float*)d_out;
    char* ws = (char*)d_ws;

    unsigned* h1r  = (unsigned*)(ws + WS_H1R);
    unsigned* cnt  = (unsigned*)(ws + WS_CNT);
    unsigned* done = (unsigned*)(ws + WS_DONE);
    unsigned long long* cand = (unsigned long long*)(ws + WS_CAND);
    unsigned long long* sup  = (unsigned long long*)(ws + WS_SUP);
    unsigned* mkeys = (unsigned*)(ws + WS_MKEYS);

    hipMemsetAsync(ws, 0, WS_MEMSET, stream);

    k_rowmax<<<M_ANCH / 256, 256, 0, stream>>>((const float4*)cls, mkeys, h1r);
    k_mega  <<<G2, BT, 0, stream>>>((const uint4*)mkeys, cls,
                                    (const float4*)reg, (const float4*)anch,
                                    h1r, cnt, done, cand, sup, out);
}